// Round 16
// baseline (126.626 us; speedup 1.0000x reference)
//
#include <hip/hip_runtime.h>
#include <math.h>

#define BB 32
#define LL 256
#define DD 16
#define HH 64
#define KK 5
#define TT 252          // LL - KK + 1
#define PP 126          // TT/2
#define SS 8064         // HH*PP
#define NCHUNK 21
#define CHUNK 384       // 21*384 = 8064; 384 = 24*16
#define NSTEP 24        // K=16 steps per chunk
#define NCT 252         // col tiles of 32: 252*32 = 8064

typedef __attribute__((ext_vector_type(8))) short bf16x8;
typedef __attribute__((ext_vector_type(16))) float f32x16;

__device__ __forceinline__ unsigned short f2bf(float f) {
  unsigned int u = __float_as_uint(f);
  u += 0x7FFFu + ((u >> 16) & 1u);          // round-to-nearest-even
  return (unsigned short)(u >> 16);
}
__device__ __forceinline__ float bf2f(unsigned short h) {
  return __uint_as_float(((unsigned int)h) << 16);
}

// ---------------- kernel 12: conv + relu + recon + pool (fused per (b,d)) --
__global__ __launch_bounds__(256) void k12_conv_recon(
    const float* __restrict__ x, const float* __restrict__ cw,
    const float* __restrict__ cb, const float* __restrict__ dw,
    const float* __restrict__ db, float* __restrict__ flat,
    unsigned short* __restrict__ mainH, unsigned short* __restrict__ mainL,
    float* __restrict__ recon) {
  __shared__ float ylds[HH * TT];   // 64*252 = 16128 f = 64512 B
  __shared__ float xs[LL];
  __shared__ float cws[HH * KK];
  __shared__ float dws[HH * KK];
  __shared__ float cbs[HH];

  int bd = blockIdx.x;              // b*DD + d
  int b = bd / DD, d = bd % DD;
  int tid = threadIdx.x;

  xs[tid] = x[((size_t)b * LL + tid) * DD + d];
  for (int i = tid; i < HH * KK; i += 256) {
    cws[i] = cw[(size_t)d * HH * KK + i];
    dws[i] = dw[(size_t)d * HH * KK + i];
  }
  if (tid < HH) cbs[tid] = cb[d * HH + tid];
  __syncthreads();

  {
    int h = tid >> 2, a = tid & 3;
    int t0 = a * 63;
    float w0 = cws[h * KK + 0], w1 = cws[h * KK + 1], w2 = cws[h * KK + 2],
          w3 = cws[h * KK + 3], w4 = cws[h * KK + 4];
    float bias = cbs[h];
    float x0 = xs[t0], x1 = xs[t0 + 1], x2 = xs[t0 + 2], x3 = xs[t0 + 3],
          x4 = xs[t0 + 4];
    float* yrow = ylds + h * TT + t0;
    #pragma unroll 7
    for (int t = 0; t < 63; ++t) {
      float yv = fmaf(w4, x4, fmaf(w3, x3, fmaf(w2, x2, fmaf(w1, x1, fmaf(w0, x0, bias)))));
      yrow[t] = fmaxf(yv, 0.f);
      x0 = x1; x1 = x2; x2 = x3; x3 = x4;
      if (t < 62) x4 = xs[t0 + t + 5];
    }
  }
  __syncthreads();

  for (int i = tid; i < HH * PP; i += 256) {
    int h = i / PP, p = i - h * PP;
    float pooled = 0.5f * (ylds[h * TT + 2 * p] + ylds[h * TT + 2 * p + 1]);
    flat[(size_t)bd * SS + i] = pooled;
    if (d == 0) {
      unsigned short hb = f2bf(pooled);
      mainH[(size_t)b * SS + i] = hb;
      mainL[(size_t)b * SS + i] = f2bf(pooled - bf2f(hb));
    }
  }

  {
    int l = tid;
    float acc = db[d];
    for (int h = 0; h < HH; ++h) {
      const float* yl = ylds + h * TT;
      #pragma unroll
      for (int j = 0; j < KK; ++j) {
        int t = l - j;
        if (t >= 0 && t < TT) acc = fmaf(yl[t], dws[h * KK + j], acc);
      }
    }
    recon[(size_t)bd * LL + l] = acc;
  }
}

// ---------------- kernel 3: partial = main @ W_attn -------------------------
// v12: wave-autonomous 32x32x16 MFMA. NO LDS, NO barriers. Each wave owns a
// 32-col x 384-k slice: per K=16 step it loads 8 W dwords (B fragment direct
// from row-major W: lane -> W[k0+(lane>>5)*8+e][n0+(lane&31)], two 128B
// segments per instr) + 2 bf16x8 A loads (L1/L2-resident main), converts
// W to hi/lo bf16 in registers, issues 3 MFMAs. 3 rotating named register
// sets give depth-2 prefetch; latency hidden by ~5 waves/SIMD.
// Layouts: A row=lane&31,k=(lane>>5)*8+e; B col=lane&31 same k;
// D col=lane&31, row=(reg&3)+8*(reg>>2)+4*(lane>>5)  [m74/m101].
__global__ __launch_bounds__(256) void k3_mfma(
    const float* __restrict__ W, const unsigned short* __restrict__ mainH,
    const unsigned short* __restrict__ mainL, float* __restrict__ partial) {
  int tid = threadIdx.x;
  int lane = tid & 63;
  int wid = blockIdx.x * 4 + (tid >> 6);   // 0..5291
  int ct = wid % NCT;
  int chunk = wid / NCT;
  int n0 = ct * 32;
  int s0 = chunk * CHUNK;
  int colq = lane & 31;        // B col / D col / A row
  int koct = lane >> 5;        // 0,1

  const float* wb = W + (size_t)(s0 + koct * 8) * SS + n0 + colq;
  const unsigned short* aHb = mainH + (size_t)colq * SS + s0 + koct * 8;
  const unsigned short* aLb = mainL + (size_t)colq * SS + s0 + koct * 8;

  f32x16 acc;
  #pragma unroll
  for (int r = 0; r < 16; ++r) acc[r] = 0.f;

  float wA0, wA1, wA2, wA3, wA4, wA5, wA6, wA7;
  float wB0, wB1, wB2, wB3, wB4, wB5, wB6, wB7;
  float wC0, wC1, wC2, wC3, wC4, wC5, wC6, wC7;
  bf16x8 aHA, aLA, aHB, aLB, aHC, aLC;

#define LOADS(P, AHR, ALR, T) {                                       \
    int tc_ = (T) < NSTEP ? (T) : NSTEP - 1;                          \
    const float* p_ = wb + (size_t)tc_ * 16 * SS;                     \
    P##0 = p_[0];                P##1 = p_[(size_t)SS];               \
    P##2 = p_[2 * (size_t)SS];   P##3 = p_[3 * (size_t)SS];           \
    P##4 = p_[4 * (size_t)SS];   P##5 = p_[5 * (size_t)SS];           \
    P##6 = p_[6 * (size_t)SS];   P##7 = p_[7 * (size_t)SS];           \
    AHR = *(const bf16x8*)(aHb + tc_ * 16);                           \
    ALR = *(const bf16x8*)(aLb + tc_ * 16); }

#define SPL(F, J) {                                                   \
    unsigned int u_ = __float_as_uint(F);                             \
    bh[J] = (short)(u_ >> 16);                                        \
    float r_ = F - __uint_as_float(u_ & 0xFFFF0000u);                 \
    bl[J] = (short)(__float_as_uint(r_) >> 16); }

#define CONSUME(P, AHR, ALR) {                                        \
    bf16x8 bh, bl;                                                    \
    SPL(P##0, 0) SPL(P##1, 1) SPL(P##2, 2) SPL(P##3, 3)               \
    SPL(P##4, 4) SPL(P##5, 5) SPL(P##6, 6) SPL(P##7, 7)               \
    acc = __builtin_amdgcn_mfma_f32_32x32x16_bf16(AHR, bh, acc, 0, 0, 0); \
    acc = __builtin_amdgcn_mfma_f32_32x32x16_bf16(AHR, bl, acc, 0, 0, 0); \
    acc = __builtin_amdgcn_mfma_f32_32x32x16_bf16(ALR, bh, acc, 0, 0, 0); }

  // prologue: steps 0,1 in flight
  LOADS(wA, aHA, aLA, 0)
  LOADS(wB, aHB, aLB, 1)

  #pragma unroll 1
  for (int t = 0; t < NSTEP; t += 3) {
    LOADS(wC, aHC, aLC, t + 2)
    CONSUME(wA, aHA, aLA)
    LOADS(wA, aHA, aLA, t + 3)
    CONSUME(wB, aHB, aLB)
    LOADS(wB, aHB, aLB, t + 4)
    CONSUME(wC, aHC, aLC)
  }

  // epilogue
  float* pp = partial + (size_t)chunk * BB * SS + n0 + colq;
  #pragma unroll
  for (int r = 0; r < 16; ++r) {
    int row = (r & 3) + 8 * (r >> 2) + 4 * koct;
    pp[(size_t)row * SS] = acc[r];
  }
#undef LOADS
#undef SPL
#undef CONSUME
}

// ---------------- kernel 3b: reduce partials -> m (float4) ------------------
__global__ __launch_bounds__(256) void k3b_reduce(
    const float4* __restrict__ partial, float4* __restrict__ m) {
  int i = blockIdx.x * 256 + threadIdx.x;      // < BB*SS/4 = 64512
  float4 s = make_float4(0.f, 0.f, 0.f, 0.f);
  #pragma unroll
  for (int c = 0; c < NCHUNK; ++c) {
    float4 v = partial[(size_t)c * (BB * SS / 4) + i];
    s.x += v.x; s.y += v.y; s.z += v.z; s.w += v.w;
  }
  m[i] = s;
}

// ---------------- kernel 4: scores[b,d'] = <m[b,:], aux[b,d',:]> ------------
__global__ __launch_bounds__(256) void k4_scores(
    const float* __restrict__ m, const float* __restrict__ flat,
    float* __restrict__ scores) {
  int bd = blockIdx.x;            // b*15 + dd
  int b = bd / 15, dd = bd % 15;
  const float* mb = m + (size_t)b * SS;
  const float* ab = flat + ((size_t)b * DD + 1 + dd) * SS;
  float p = 0.f;
  for (int s = threadIdx.x; s < SS; s += 256) p = fmaf(mb[s], ab[s], p);
  #pragma unroll
  for (int o = 32; o; o >>= 1) p += __shfl_xor(p, o);
  __shared__ float red[4];
  if ((threadIdx.x & 63) == 0) red[threadIdx.x >> 6] = p;
  __syncthreads();
  if (threadIdx.x == 0) scores[bd] = red[0] + red[1] + red[2] + red[3];
}

// ---------------- kernel 5: softmax over 15 ---------------------------------
__global__ __launch_bounds__(64) void k5_softmax(
    const float* __restrict__ scores, float* __restrict__ attn_out) {
  int b = blockIdx.x;
  int lane = threadIdx.x;
  float v = (lane < 15) ? scores[b * 15 + lane] : -INFINITY;
  float mx = v;
  #pragma unroll
  for (int o = 32; o; o >>= 1) mx = fmaxf(mx, __shfl_xor(mx, o));
  float e = (lane < 15) ? expf(v - mx) : 0.f;
  float sum = e;
  #pragma unroll
  for (int o = 32; o; o >>= 1) sum += __shfl_xor(sum, o);
  if (lane < 15) attn_out[b * 15 + lane] = e / sum;
}

// ---------------- kernel 6: main copy + weighted sum ------------------------
__global__ __launch_bounds__(256) void k6_out(
    const float* __restrict__ flat, const float* __restrict__ attn,
    float* __restrict__ out) {
  int b = blockIdx.y;
  int s = blockIdx.x * 256 + threadIdx.x;
  if (s >= SS) return;
  const float* fb = flat + (size_t)b * DD * SS;
  out[(size_t)b * 2 * SS + s] = fb[s];
  float w = 0.f;
  #pragma unroll
  for (int d = 0; d < 15; ++d)
    w = fmaf(attn[b * 15 + d], fb[(size_t)(1 + d) * SS + s], w);
  out[(size_t)b * 2 * SS + SS + s] = w;
}

// ---------------------------------------------------------------------------
extern "C" void kernel_launch(void* const* d_in, const int* in_sizes, int n_in,
                              void* d_out, int out_size, void* d_ws, size_t ws_size,
                              hipStream_t stream) {
  const float* x        = (const float*)d_in[0];
  const float* conv_w   = (const float*)d_in[1];
  const float* conv_b   = (const float*)d_in[2];
  const float* deconv_w = (const float*)d_in[3];
  const float* deconv_b = (const float*)d_in[4];
  const float* W_attn   = (const float*)d_in[5];
  float* out = (float*)d_out;

  // output layout: [ out (516096) | attn (480) | recon (131072) ]
  const size_t ATTN_OFF  = (size_t)BB * 2 * SS;        // 516096
  const size_t RECON_OFF = ATTN_OFF + (size_t)BB * 15; // 516576

  // workspace layout; all 16B-aligned
  float* ws      = (float*)d_ws;
  float* partial = ws;                                        // 21*32*8064 f
  float* flat    = partial + (size_t)NCHUNK * BB * SS;        // 4,128,768 f
  unsigned short* mainH = (unsigned short*)(flat + (size_t)BB * DD * SS);
  unsigned short* mainL = mainH + (size_t)BB * SS;
  float* m       = (float*)(mainL + (size_t)BB * SS);
  float* scores  = m + (size_t)BB * SS;

  // 1) fused conv+relu+recon+pool (+ bf16 hi/lo split of main)
  k12_conv_recon<<<dim3(BB * DD), dim3(256), 0, stream>>>(
      x, conv_w, conv_b, deconv_w, deconv_b, flat, mainH, mainL, out + RECON_OFF);

  // 2) big matmul partials via wave-autonomous 32x32 MFMA (no LDS/barriers)
  k3_mfma<<<dim3((NCT * NCHUNK) / 4), dim3(256), 0, stream>>>(
      W_attn, mainH, mainL, partial);

  // 3) reduce -> m
  k3b_reduce<<<dim3((BB * SS / 4) / 256), dim3(256), 0, stream>>>(
      (const float4*)partial, (float4*)m);

  // 4) scores
  k4_scores<<<dim3(BB * 15), dim3(256), 0, stream>>>(m, flat, scores);

  // 5) softmax -> attn section of out
  k5_softmax<<<dim3(BB), dim3(64), 0, stream>>>(scores, out + ATTN_OFF);

  // 6) main copy + weighted
  k6_out<<<dim3((SS + 255) / 256, BB), dim3(256), 0, stream>>>(
      flat, out + ATTN_OFF, out);
}

// Round 17
// 107.689 us; speedup vs baseline: 1.1759x; 1.1759x over previous
//
#include <hip/hip_runtime.h>
#include <math.h>

#define BB 32
#define LL 256
#define DD 16
#define HH 64
#define KK 5
#define TT 252          // LL - KK + 1
#define PP 126          // TT/2
#define SS 8064         // HH*PP
#define NCHUNK 21
#define CHUNK 384       // 21*384 = 8064
#define NSTEP 24        // K=16 steps per chunk
#define NCT 252         // col tiles of 32: 252*32 = 8064
#define GSTEPS 504      // SS/16 global K=16 steps

typedef __attribute__((ext_vector_type(8))) short bf16x8;
typedef __attribute__((ext_vector_type(16))) float f32x16;

__device__ __forceinline__ unsigned short f2bf(float f) {
  unsigned int u = __float_as_uint(f);
  u += 0x7FFFu + ((u >> 16) & 1u);          // round-to-nearest-even
  return (unsigned short)(u >> 16);
}
__device__ __forceinline__ float bf2f(unsigned short h) {
  return __uint_as_float(((unsigned int)h) << 16);
}

// ---------------- kernel 12: conv + relu + recon + pool (fused per (b,d)) --
__global__ __launch_bounds__(256) void k12_conv_recon(
    const float* __restrict__ x, const float* __restrict__ cw,
    const float* __restrict__ cb, const float* __restrict__ dw,
    const float* __restrict__ db, float* __restrict__ flat,
    unsigned short* __restrict__ mainH, unsigned short* __restrict__ mainL,
    float* __restrict__ recon) {
  __shared__ float ylds[HH * TT];   // 64*252 = 16128 f = 64512 B
  __shared__ float xs[LL];
  __shared__ float cws[HH * KK];
  __shared__ float dws[HH * KK];
  __shared__ float cbs[HH];

  int bd = blockIdx.x;              // b*DD + d
  int b = bd / DD, d = bd % DD;
  int tid = threadIdx.x;

  xs[tid] = x[((size_t)b * LL + tid) * DD + d];
  for (int i = tid; i < HH * KK; i += 256) {
    cws[i] = cw[(size_t)d * HH * KK + i];
    dws[i] = dw[(size_t)d * HH * KK + i];
  }
  if (tid < HH) cbs[tid] = cb[d * HH + tid];
  __syncthreads();

  {
    int h = tid >> 2, a = tid & 3;
    int t0 = a * 63;
    float w0 = cws[h * KK + 0], w1 = cws[h * KK + 1], w2 = cws[h * KK + 2],
          w3 = cws[h * KK + 3], w4 = cws[h * KK + 4];
    float bias = cbs[h];
    float x0 = xs[t0], x1 = xs[t0 + 1], x2 = xs[t0 + 2], x3 = xs[t0 + 3],
          x4 = xs[t0 + 4];
    float* yrow = ylds + h * TT + t0;
    #pragma unroll 7
    for (int t = 0; t < 63; ++t) {
      float yv = fmaf(w4, x4, fmaf(w3, x3, fmaf(w2, x2, fmaf(w1, x1, fmaf(w0, x0, bias)))));
      yrow[t] = fmaxf(yv, 0.f);
      x0 = x1; x1 = x2; x2 = x3; x3 = x4;
      if (t < 62) x4 = xs[t0 + t + 5];
    }
  }
  __syncthreads();

  for (int i = tid; i < HH * PP; i += 256) {
    int h = i / PP, p = i - h * PP;
    float pooled = 0.5f * (ylds[h * TT + 2 * p] + ylds[h * TT + 2 * p + 1]);
    flat[(size_t)bd * SS + i] = pooled;
    if (d == 0) {
      unsigned short hb = f2bf(pooled);
      mainH[(size_t)b * SS + i] = hb;
      mainL[(size_t)b * SS + i] = f2bf(pooled - bf2f(hb));
    }
  }

  {
    int l = tid;
    float acc = db[d];
    for (int h = 0; h < HH; ++h) {
      const float* yl = ylds + h * TT;
      #pragma unroll
      for (int j = 0; j < KK; ++j) {
        int t = l - j;
        if (t >= 0 && t < TT) acc = fmaf(yl[t], dws[h * KK + j], acc);
      }
    }
    recon[(size_t)bd * LL + l] = acc;
  }
}

// ---------------- kernel 2c: build fragment-ready A -------------------------
// Afrag[gt][lane] = bf16x8 at mainX[(lane&31)*SS + gt*16 + (lane>>5)*8]
// One contiguous 16B load+store per thread; 2MB total one-shot.
__global__ __launch_bounds__(256) void k2c_afrag(
    const unsigned short* __restrict__ mainH,
    const unsigned short* __restrict__ mainL,
    unsigned short* __restrict__ afragH, unsigned short* __restrict__ afragL) {
  int i = blockIdx.x * 256 + threadIdx.x;   // < GSTEPS*64 = 32256
  int gt = i >> 6, l = i & 63;
  size_t src = (size_t)(l & 31) * SS + gt * 16 + (l >> 5) * 8;
  *(bf16x8*)&afragH[(size_t)i * 8] = *(const bf16x8*)(mainH + src);
  *(bf16x8*)&afragL[(size_t)i * 8] = *(const bf16x8*)(mainL + src);
}

// ---------------- kernel 3: partial = main @ W_attn -------------------------
// v13: wave-autonomous 32x32x16 MFMA, no LDS/barriers (round-16 structure,
// layouts verified passing), with the A gather replaced by ONE coalesced
// bf16x8 load from the fragment-ready Afrag array (1KB/instr, L2-broadcast
// across the 252 col-waves sharing each fragment). W: 8 dword loads/step,
// each two fully-used 128B lines. 3 rotating named register sets.
__global__ __launch_bounds__(256) void k3_mfma(
    const float* __restrict__ W, const unsigned short* __restrict__ afragH,
    const unsigned short* __restrict__ afragL, float* __restrict__ partial) {
  int tid = threadIdx.x;
  int lane = tid & 63;
  int wid = blockIdx.x * 4 + (tid >> 6);   // 0..5291
  int ct = wid % NCT;
  int chunk = wid / NCT;
  int n0 = ct * 32;
  int s0 = chunk * CHUNK;
  int colq = lane & 31;        // B col / D col
  int koct = lane >> 5;        // 0,1

  const float* wb = W + (size_t)(s0 + koct * 8) * SS + n0 + colq;
  const unsigned short* afH = afragH + (size_t)(chunk * NSTEP) * 512 + lane * 8;
  const unsigned short* afL = afragL + (size_t)(chunk * NSTEP) * 512 + lane * 8;

  f32x16 acc;
  #pragma unroll
  for (int r = 0; r < 16; ++r) acc[r] = 0.f;

  float wA0, wA1, wA2, wA3, wA4, wA5, wA6, wA7;
  float wB0, wB1, wB2, wB3, wB4, wB5, wB6, wB7;
  float wC0, wC1, wC2, wC3, wC4, wC5, wC6, wC7;
  bf16x8 aHA, aLA, aHB, aLB, aHC, aLC;

#define LOADS(P, AHR, ALR, T) {                                       \
    int tc_ = (T) < NSTEP ? (T) : NSTEP - 1;                          \
    const float* p_ = wb + (size_t)tc_ * 16 * SS;                     \
    P##0 = p_[0];                P##1 = p_[(size_t)SS];               \
    P##2 = p_[2 * (size_t)SS];   P##3 = p_[3 * (size_t)SS];           \
    P##4 = p_[4 * (size_t)SS];   P##5 = p_[5 * (size_t)SS];           \
    P##6 = p_[6 * (size_t)SS];   P##7 = p_[7 * (size_t)SS];           \
    AHR = *(const bf16x8*)(afH + (size_t)tc_ * 512);                  \
    ALR = *(const bf16x8*)(afL + (size_t)tc_ * 512); }

#define SPL(F, J) {                                                   \
    unsigned int u_ = __float_as_uint(F);                             \
    bh[J] = (short)(u_ >> 16);                                        \
    float r_ = F - __uint_as_float(u_ & 0xFFFF0000u);                 \
    bl[J] = (short)(__float_as_uint(r_) >> 16); }

#define CONSUME(P, AHR, ALR) {                                        \
    bf16x8 bh, bl;                                                    \
    SPL(P##0, 0) SPL(P##1, 1) SPL(P##2, 2) SPL(P##3, 3)               \
    SPL(P##4, 4) SPL(P##5, 5) SPL(P##6, 6) SPL(P##7, 7)               \
    acc = __builtin_amdgcn_mfma_f32_32x32x16_bf16(AHR, bh, acc, 0, 0, 0); \
    acc = __builtin_amdgcn_mfma_f32_32x32x16_bf16(AHR, bl, acc, 0, 0, 0); \
    acc = __builtin_amdgcn_mfma_f32_32x32x16_bf16(ALR, bh, acc, 0, 0, 0); }

  // prologue: steps 0,1 in flight
  LOADS(wA, aHA, aLA, 0)
  LOADS(wB, aHB, aLB, 1)

  #pragma unroll 1
  for (int t = 0; t < NSTEP; t += 3) {
    LOADS(wC, aHC, aLC, t + 2)
    CONSUME(wA, aHA, aLA)
    LOADS(wA, aHA, aLA, t + 3)
    CONSUME(wB, aHB, aLB)
    LOADS(wB, aHB, aLB, t + 4)
    CONSUME(wC, aHC, aLC)
  }

  // epilogue: D col=lane&31, row=(reg&3)+8*(reg>>2)+4*koct  [m74/m101]
  float* pp = partial + (size_t)chunk * BB * SS + n0 + colq;
  #pragma unroll
  for (int r = 0; r < 16; ++r) {
    int row = (r & 3) + 8 * (r >> 2) + 4 * koct;
    pp[(size_t)row * SS] = acc[r];
  }
#undef LOADS
#undef SPL
#undef CONSUME
}

// ---------------- kernel 3b: reduce partials -> m (float4) ------------------
__global__ __launch_bounds__(256) void k3b_reduce(
    const float4* __restrict__ partial, float4* __restrict__ m) {
  int i = blockIdx.x * 256 + threadIdx.x;      // < BB*SS/4 = 64512
  float4 s = make_float4(0.f, 0.f, 0.f, 0.f);
  #pragma unroll
  for (int c = 0; c < NCHUNK; ++c) {
    float4 v = partial[(size_t)c * (BB * SS / 4) + i];
    s.x += v.x; s.y += v.y; s.z += v.z; s.w += v.w;
  }
  m[i] = s;
}

// ---------------- kernel 4: scores[b,d'] = <m[b,:], aux[b,d',:]> ------------
__global__ __launch_bounds__(256) void k4_scores(
    const float* __restrict__ m, const float* __restrict__ flat,
    float* __restrict__ scores) {
  int bd = blockIdx.x;            // b*15 + dd
  int b = bd / 15, dd = bd % 15;
  const float* mb = m + (size_t)b * SS;
  const float* ab = flat + ((size_t)b * DD + 1 + dd) * SS;
  float p = 0.f;
  for (int s = threadIdx.x; s < SS; s += 256) p = fmaf(mb[s], ab[s], p);
  #pragma unroll
  for (int o = 32; o; o >>= 1) p += __shfl_xor(p, o);
  __shared__ float red[4];
  if ((threadIdx.x & 63) == 0) red[threadIdx.x >> 6] = p;
  __syncthreads();
  if (threadIdx.x == 0) scores[bd] = red[0] + red[1] + red[2] + red[3];
}

// ---------------- kernel 5: softmax over 15 ---------------------------------
__global__ __launch_bounds__(64) void k5_softmax(
    const float* __restrict__ scores, float* __restrict__ attn_out) {
  int b = blockIdx.x;
  int lane = threadIdx.x;
  float v = (lane < 15) ? scores[b * 15 + lane] : -INFINITY;
  float mx = v;
  #pragma unroll
  for (int o = 32; o; o >>= 1) mx = fmaxf(mx, __shfl_xor(mx, o));
  float e = (lane < 15) ? expf(v - mx) : 0.f;
  float sum = e;
  #pragma unroll
  for (int o = 32; o; o >>= 1) sum += __shfl_xor(sum, o);
  if (lane < 15) attn_out[b * 15 + lane] = e / sum;
}

// ---------------- kernel 6: main copy + weighted sum ------------------------
__global__ __launch_bounds__(256) void k6_out(
    const float* __restrict__ flat, const float* __restrict__ attn,
    float* __restrict__ out) {
  int b = blockIdx.y;
  int s = blockIdx.x * 256 + threadIdx.x;
  if (s >= SS) return;
  const float* fb = flat + (size_t)b * DD * SS;
  out[(size_t)b * 2 * SS + s] = fb[s];
  float w = 0.f;
  #pragma unroll
  for (int d = 0; d < 15; ++d)
    w = fmaf(attn[b * 15 + d], fb[(size_t)(1 + d) * SS + s], w);
  out[(size_t)b * 2 * SS + SS + s] = w;
}

// ---------------------------------------------------------------------------
extern "C" void kernel_launch(void* const* d_in, const int* in_sizes, int n_in,
                              void* d_out, int out_size, void* d_ws, size_t ws_size,
                              hipStream_t stream) {
  const float* x        = (const float*)d_in[0];
  const float* conv_w   = (const float*)d_in[1];
  const float* conv_b   = (const float*)d_in[2];
  const float* deconv_w = (const float*)d_in[3];
  const float* deconv_b = (const float*)d_in[4];
  const float* W_attn   = (const float*)d_in[5];
  float* out = (float*)d_out;

  // output layout: [ out (516096) | attn (480) | recon (131072) ]
  const size_t ATTN_OFF  = (size_t)BB * 2 * SS;        // 516096
  const size_t RECON_OFF = ATTN_OFF + (size_t)BB * 15; // 516576

  // workspace layout; all 16B-aligned
  float* ws      = (float*)d_ws;
  float* partial = ws;                                        // 21*32*8064 f
  float* flat    = partial + (size_t)NCHUNK * BB * SS;        // 4,128,768 f
  unsigned short* mainH  = (unsigned short*)(flat + (size_t)BB * DD * SS);
  unsigned short* mainL  = mainH + (size_t)BB * SS;           // 258,048 u16
  unsigned short* afragH = mainL + (size_t)BB * SS;           // 258,048 u16
  unsigned short* afragL = afragH + (size_t)GSTEPS * 512;     // 258,048 u16
  float* m       = (float*)(afragL + (size_t)GSTEPS * 512);
  float* scores  = m + (size_t)BB * SS;

  // 1) fused conv+relu+recon+pool (+ bf16 hi/lo split of main)
  k12_conv_recon<<<dim3(BB * DD), dim3(256), 0, stream>>>(
      x, conv_w, conv_b, deconv_w, deconv_b, flat, mainH, mainL, out + RECON_OFF);

  // 1c) fragment-ready A
  k2c_afrag<<<dim3(GSTEPS * 64 / 256), dim3(256), 0, stream>>>(
      mainH, mainL, afragH, afragL);

  // 2) big matmul partials via wave-autonomous 32x32 MFMA
  k3_mfma<<<dim3((NCT * NCHUNK) / 4), dim3(256), 0, stream>>>(
      W_attn, afragH, afragL, partial);

  // 3) reduce -> m
  k3b_reduce<<<dim3((BB * SS / 4) / 256), dim3(256), 0, stream>>>(
      (const float4*)partial, (float4*)m);

  // 4) scores
  k4_scores<<<dim3(BB * 15), dim3(256), 0, stream>>>(m, flat, scores);

  // 5) softmax -> attn section of out
  k5_softmax<<<dim3(BB), dim3(64), 0, stream>>>(scores, out + ATTN_OFF);

  // 6) main copy + weighted
  k6_out<<<dim3((SS + 255) / 256, BB), dim3(256), 0, stream>>>(
      flat, out + ATTN_OFF, out);
}